// Round 1
// baseline (614.970 us; speedup 1.0000x reference)
//
#include <hip/hip_runtime.h>
#include <hip/hip_fp16.h>

#define BATCH_N   2048
#define EMB_D_    768
#define PROJ_D_   128
#define QUEUE_N   32768
#define HARD_K_   512
static constexpr float INV_T = 1.0f / 0.07f;

// ---------------------------------------------------------------------------
// GEMM C = act(A @ B + bias): A (M x K) row-major, B (K x N) row-major.
// 64x64 tile, BK=16, 256 threads, 4x4 micro-tile. LDS stride 68 (pad, f4-aligned).
// ---------------------------------------------------------------------------
template<bool RELU>
__global__ void __launch_bounds__(256) gemm_bias(const float* __restrict__ A,
                                                 const float* __restrict__ B,
                                                 const float* __restrict__ bias,
                                                 float* __restrict__ C,
                                                 int M, int N, int K) {
    __shared__ float As[16][68];
    __shared__ float Bs[16][68];
    const int t  = threadIdx.x;
    const int tx = t & 15, ty = t >> 4;
    const int m0 = blockIdx.y * 64, n0 = blockIdx.x * 64;
    const int arow = t >> 2, aks = (t & 3) * 4;   // A tile: 64 rows x 16 k
    const int bkk  = t >> 4, bns = (t & 15) * 4;  // B tile: 16 k x 64 n
    float acc[4][4] = {};
    for (int k0 = 0; k0 < K; k0 += 16) {
        float4 av = *(const float4*)&A[(size_t)(m0 + arow) * K + k0 + aks];
        float4 bv = *(const float4*)&B[(size_t)(k0 + bkk) * N + n0 + bns];
        __syncthreads();
        As[aks + 0][arow] = av.x; As[aks + 1][arow] = av.y;
        As[aks + 2][arow] = av.z; As[aks + 3][arow] = av.w;
        *(float4*)&Bs[bkk][bns] = bv;
        __syncthreads();
        #pragma unroll
        for (int kk = 0; kk < 16; kk++) {
            float4 a4 = *(const float4*)&As[kk][ty * 4];
            float4 b4 = *(const float4*)&Bs[kk][tx * 4];
            float a[4] = {a4.x, a4.y, a4.z, a4.w};
            float b[4] = {b4.x, b4.y, b4.z, b4.w};
            #pragma unroll
            for (int i = 0; i < 4; i++)
                #pragma unroll
                for (int j = 0; j < 4; j++) acc[i][j] += a[i] * b[j];
        }
    }
    const int nbase = n0 + tx * 4;
    const float4 bb = *(const float4*)&bias[nbase];
    const float bs[4] = {bb.x, bb.y, bb.z, bb.w};
    #pragma unroll
    for (int i = 0; i < 4; i++) {
        int m = m0 + ty * 4 + i;
        float4 o;
        float v0 = acc[i][0] + bs[0], v1 = acc[i][1] + bs[1];
        float v2 = acc[i][2] + bs[2], v3 = acc[i][3] + bs[3];
        if (RELU) { v0 = fmaxf(v0, 0.f); v1 = fmaxf(v1, 0.f); v2 = fmaxf(v2, 0.f); v3 = fmaxf(v3, 0.f); }
        o.x = v0; o.y = v1; o.z = v2; o.w = v3;
        *(float4*)&C[(size_t)m * N + nbase] = o;
    }
}

// ---------------------------------------------------------------------------
// NT GEMM: C[m][n] = sum_k A[m][k]*B[n][k].  A (M x K), B (N x K), row-major.
// MASK=true: store fp16, same-label entries -> -65504.  MASK=false: raw fp32.
// ---------------------------------------------------------------------------
template<typename OutT, bool MASK>
__global__ void __launch_bounds__(256) gemm_nt(const float* __restrict__ A,
                                               const float* __restrict__ Bm,
                                               OutT* __restrict__ C,
                                               int M, int N, int K,
                                               const int* __restrict__ labA,
                                               const int* __restrict__ labB) {
    __shared__ float As[16][68];
    __shared__ float Bs[16][68];
    const int t  = threadIdx.x;
    const int tx = t & 15, ty = t >> 4;
    const int m0 = blockIdx.y * 64, n0 = blockIdx.x * 64;
    const int lrow = t >> 2, lks = (t & 3) * 4;
    float acc[4][4] = {};
    for (int k0 = 0; k0 < K; k0 += 16) {
        float4 av = *(const float4*)&A [(size_t)(m0 + lrow) * K + k0 + lks];
        float4 bv = *(const float4*)&Bm[(size_t)(n0 + lrow) * K + k0 + lks];
        __syncthreads();
        As[lks + 0][lrow] = av.x; As[lks + 1][lrow] = av.y;
        As[lks + 2][lrow] = av.z; As[lks + 3][lrow] = av.w;
        Bs[lks + 0][lrow] = bv.x; Bs[lks + 1][lrow] = bv.y;
        Bs[lks + 2][lrow] = bv.z; Bs[lks + 3][lrow] = bv.w;
        __syncthreads();
        #pragma unroll
        for (int kk = 0; kk < 16; kk++) {
            float4 a4 = *(const float4*)&As[kk][ty * 4];
            float4 b4 = *(const float4*)&Bs[kk][tx * 4];
            float a[4] = {a4.x, a4.y, a4.z, a4.w};
            float b[4] = {b4.x, b4.y, b4.z, b4.w};
            #pragma unroll
            for (int i = 0; i < 4; i++)
                #pragma unroll
                for (int j = 0; j < 4; j++) acc[i][j] += a[i] * b[j];
        }
    }
    const int nbase = n0 + tx * 4;
    #pragma unroll
    for (int i = 0; i < 4; i++) {
        const int m = m0 + ty * 4 + i;
        if constexpr (MASK) {
            const int li = labA[m];
            union { __half h[4]; uint2 u; } pk;
            #pragma unroll
            for (int j = 0; j < 4; j++) {
                const int q = labB[nbase + j];
                float v = (q != li && q >= 0) ? acc[i][j] : -65504.0f;
                pk.h[j] = __float2half(v);
            }
            *(uint2*)((__half*)C + (size_t)m * N + nbase) = pk.u;
        } else {
            float4 o = make_float4(acc[i][0], acc[i][1], acc[i][2], acc[i][3]);
            *(float4*)((float*)C + (size_t)m * N + nbase) = o;
        }
    }
}

// ---------------------------------------------------------------------------
// Row L2-normalize z (2048 x 128), in place. One block (128 thr) per row.
// ---------------------------------------------------------------------------
__global__ void normalize_rows(float* __restrict__ z) {
    const int row = blockIdx.x, t = threadIdx.x;
    float v = z[(size_t)row * PROJ_D_ + t];
    float ss = v * v;
    #pragma unroll
    for (int o = 32; o > 0; o >>= 1) ss += __shfl_down(ss, o);
    __shared__ float s2[2];
    if ((t & 63) == 0) s2[t >> 6] = ss;
    __syncthreads();
    const float tot = s2[0] + s2[1];
    z[(size_t)row * PROJ_D_ + t] = v / sqrtf(tot);
}

// ---------------------------------------------------------------------------
// Histogram crossing search over hist[1024]: find bin b with
// count(bins > b) < target <= count(bins >= b). Writes *s_bin, *s_chi.
// ---------------------------------------------------------------------------
__device__ __forceinline__ void find_crossing(int* hist, int* grp, int target,
                                              int* s_bin, int* s_chi) {
    const int t = threadIdx.x;
    const int b0 = hist[4*t], b1 = hist[4*t+1], b2 = hist[4*t+2], b3 = hist[4*t+3];
    grp[t] = b0 + b1 + b2 + b3;
    __syncthreads();
    for (int off = 1; off < 256; off <<= 1) {         // suffix-sum (inclusive)
        int add = (t + off < 256) ? grp[t + off] : 0;
        __syncthreads();
        grp[t] += add;
        __syncthreads();
    }
    int cab = (t < 255) ? grp[t + 1] : 0;             // count above bin 4t+3
    const int hb[4] = {b0, b1, b2, b3};
    #pragma unroll
    for (int i = 3; i >= 0; i--) {
        const int h = hb[i];
        if (cab < target && cab + h >= target) { *s_bin = 4*t + i; *s_chi = cab; }
        cab += h;
    }
    __syncthreads();
}

// ---------------------------------------------------------------------------
// Per-row exact lse over top-512 of masked fp16 sims (one block per row).
// Two-level 1024-bin histogram select (resolution 2/1024/512 ≈ 1.9e-6), then
// sum exp((v-max)/T) for v > thr with boundary-count compensation.
// ---------------------------------------------------------------------------
__global__ void __launch_bounds__(256) topk_lse(const __half* __restrict__ sims,
                                                float* __restrict__ lseq) {
    const int row = blockIdx.x, t = threadIdx.x;
    const uint4* rowp = (const uint4*)(sims + (size_t)row * QUEUE_N);
    __shared__ int hist[1024];
    __shared__ int grp[256];
    __shared__ int s_bin, s_chi, s_bin2, s_chi2;
    __shared__ float scf[4];
    __shared__ int sci[4];

    for (int k = t; k < 1024; k += 256) hist[k] = 0;
    __syncthreads();

    // pass 1: row max + coarse histogram over [-1, 1], 1024 bins
    float mloc = -1e30f;
    for (int k = 0; k < 16; k++) {
        uint4 u = rowp[k * 256 + t];
        const __half2* hp = (const __half2*)&u;
        #pragma unroll
        for (int q = 0; q < 4; q++) {
            float2 f = __half22float2(hp[q]);
            #pragma unroll
            for (int e = 0; e < 2; e++) {
                const float v = e ? f.y : f.x;
                mloc = fmaxf(mloc, v);
                const float bf = fminf(fmaxf((v + 1.0f) * 512.0f, 0.0f), 1023.0f);
                atomicAdd(&hist[(int)bf], 1);
            }
        }
    }
    #pragma unroll
    for (int o = 32; o > 0; o >>= 1) mloc = fmaxf(mloc, __shfl_xor(mloc, o));
    if ((t & 63) == 0) scf[t >> 6] = mloc;
    __syncthreads();
    const float m = fmaxf(fmaxf(scf[0], scf[1]), fmaxf(scf[2], scf[3]));

    find_crossing(hist, grp, HARD_K_, &s_bin, &s_chi);
    const int   bin1 = s_bin;
    const int   chi1 = s_chi;
    const float lo   = -1.0f + bin1 * (1.0f / 512.0f);

    // pass 2: refine within the crossing bin
    for (int k = t; k < 1024; k += 256) hist[k] = 0;
    __syncthreads();
    for (int k = 0; k < 16; k++) {
        uint4 u = rowp[k * 256 + t];
        const __half2* hp = (const __half2*)&u;
        #pragma unroll
        for (int q = 0; q < 4; q++) {
            float2 f = __half22float2(hp[q]);
            #pragma unroll
            for (int e = 0; e < 2; e++) {
                const float v = e ? f.y : f.x;
                const float bf = fminf(fmaxf((v + 1.0f) * 512.0f, 0.0f), 1023.0f);
                if ((int)bf == bin1) {
                    const float sf = fminf(fmaxf((v - lo) * 524288.0f, 0.0f), 1023.0f);
                    atomicAdd(&hist[(int)sf], 1);
                }
            }
        }
    }
    __syncthreads();
    find_crossing(hist, grp, HARD_K_ - chi1, &s_bin2, &s_chi2);
    const float thr = lo + s_bin2 * (1.0f / 524288.0f);

    // pass 3: exp-sum over v > thr, compensate boundary count to exactly 512
    float sl = 0.0f; int cg = 0;
    for (int k = 0; k < 16; k++) {
        uint4 u = rowp[k * 256 + t];
        const __half2* hp = (const __half2*)&u;
        #pragma unroll
        for (int q = 0; q < 4; q++) {
            float2 f = __half22float2(hp[q]);
            #pragma unroll
            for (int e = 0; e < 2; e++) {
                const float v = e ? f.y : f.x;
                if (v > thr) { cg++; sl += __expf((v - m) * INV_T); }
            }
        }
    }
    #pragma unroll
    for (int o = 32; o > 0; o >>= 1) { sl += __shfl_xor(sl, o); cg += __shfl_xor(cg, o); }
    if ((t & 63) == 0) { scf[t >> 6] = sl; sci[t >> 6] = cg; }
    __syncthreads();
    if (t == 0) {
        const float slt = scf[0] + scf[1] + scf[2] + scf[3];
        const int   cgt = sci[0] + sci[1] + sci[2] + sci[3];
        const float sadj = slt + ((float)HARD_K_ - (float)cgt) * __expf((thr - m) * INV_T);
        lseq[row] = m * INV_T + __logf(sadj);
    }
}

// ---------------------------------------------------------------------------
// Per-row batch lse + positive-pair loss. One block (256 thr) per row.
// ---------------------------------------------------------------------------
__global__ void __launch_bounds__(256) batch_row_loss(const float* __restrict__ S,
                                                      const int* __restrict__ labels,
                                                      const float* __restrict__ lse_queue,
                                                      float* __restrict__ loss_sum,
                                                      unsigned int* __restrict__ pair_count) {
    const int row = blockIdx.x, t = threadIdx.x;
    __shared__ int lab[BATCH_N];
    __shared__ float wm[4], wsum[4], Lsh;
    __shared__ float rp[4]; __shared__ int rc[4];
    for (int k = t; k < BATCH_N; k += 256) lab[k] = labels[k];
    __syncthreads();
    const int myLab = lab[row];
    const float* rowp = S + (size_t)row * BATCH_N;

    float v[8];
    float mm = -1e30f, ss = 0.0f;
    #pragma unroll
    for (int k = 0; k < 8; k++) {
        const int j = t + 256 * k;
        v[k] = rowp[j] * INV_T;
        if (lab[j] != myLab) {
            const float sv = v[k];
            if (sv > mm) { ss = ss * __expf(mm - sv) + 1.0f; mm = sv; }
            else         { ss += __expf(sv - mm); }
        }
    }
    // wave reduce (m,s)
    #pragma unroll
    for (int o = 32; o > 0; o >>= 1) {
        const float om = __shfl_xor(mm, o), os = __shfl_xor(ss, o);
        const float nm = fmaxf(mm, om);
        ss = ss * __expf(mm - nm) + os * __expf(om - nm);
        mm = nm;
    }
    if ((t & 63) == 0) { wm[t >> 6] = mm; wsum[t >> 6] = ss; }
    __syncthreads();
    if (t == 0) {
        float M = -1e30f, Sx = 0.0f;
        for (int w = 0; w < 4; w++) {
            const float nm = fmaxf(M, wm[w]);
            Sx = Sx * __expf(M - nm) + wsum[w] * __expf(wm[w] - nm);
            M = nm;
        }
        const float lseb = (Sx > 0.0f) ? M + __logf(Sx) : -1e30f;
        const float Lq = lse_queue[row];
        const float mx = fmaxf(lseb, Lq), mn = fminf(lseb, Lq);
        Lsh = mx + log1pf(__expf(mn - mx));
    }
    __syncthreads();
    const float L = Lsh;

    float part = 0.0f; int cnt = 0;
    #pragma unroll
    for (int k = 0; k < 8; k++) {
        const int j = t + 256 * k;
        if (lab[j] == myLab && j != row) {
            const float sv = v[k];
            const float mx = fmaxf(sv, L), mn = fminf(sv, L);
            part += (mx + log1pf(__expf(mn - mx))) - sv;
            cnt++;
        }
    }
    #pragma unroll
    for (int o = 32; o > 0; o >>= 1) { part += __shfl_xor(part, o); cnt += __shfl_xor(cnt, o); }
    if ((t & 63) == 0) { rp[t >> 6] = part; rc[t >> 6] = cnt; }
    __syncthreads();
    if (t == 0) {
        atomicAdd(loss_sum, rp[0] + rp[1] + rp[2] + rp[3]);
        atomicAdd(pair_count, (unsigned int)(rc[0] + rc[1] + rc[2] + rc[3]));
    }
}

__global__ void finalize_loss(const float* __restrict__ loss_sum,
                              const unsigned int* __restrict__ cnt,
                              float* __restrict__ out) {
    if (blockIdx.x == 0 && threadIdx.x == 0) {
        const unsigned int c = *cnt;
        out[0] = (c > 0) ? (*loss_sum / (float)c) : 0.0f;
    }
}

// ---------------------------------------------------------------------------
extern "C" void kernel_launch(void* const* d_in, const int* in_sizes, int n_in,
                              void* d_out, int out_size, void* d_ws, size_t ws_size,
                              hipStream_t stream) {
    const float* emb    = (const float*)d_in[0];
    const int*   labels = (const int*)  d_in[1];
    const float* W1     = (const float*)d_in[2];
    const float* b1     = (const float*)d_in[3];
    const float* W2     = (const float*)d_in[4];
    const float* b2     = (const float*)d_in[5];
    const float* queue  = (const float*)d_in[6];
    const int*   qlab   = (const int*)  d_in[7];

    char* ws = (char*)d_ws;
    // layout (bytes)
    __half* simsq = (__half*)(ws);                       // 2048*32768*2 = 134217728
    float*  Sbuf  = (float*) (ws + 134217728);           // 2048*2048*4  =  16777216
    float*  h     = (float*) (ws + 150994944);           // 2048*768*4   =   6291456
    float*  z     = (float*) (ws + 157286400);           // 2048*128*4   =   1048576
    float*  lseq  = (float*) (ws + 158334976);           // 2048*4       =      8192
    float*         accf = (float*)       (ws + 158343168);
    unsigned int*  accc = (unsigned int*)(ws + 158343172);

    hipMemsetAsync(ws + 158343168, 0, 8, stream);

    dim3 blk(256);
    // h = relu(emb @ W1 + b1)
    gemm_bias<true ><<<dim3(EMB_D_ / 64, BATCH_N / 64), blk, 0, stream>>>(emb, W1, b1, h, BATCH_N, EMB_D_, EMB_D_);
    // z = h @ W2 + b2
    gemm_bias<false><<<dim3(PROJ_D_ / 64, BATCH_N / 64), blk, 0, stream>>>(h, W2, b2, z, BATCH_N, PROJ_D_, EMB_D_);
    normalize_rows<<<BATCH_N, PROJ_D_, 0, stream>>>(z);
    // S = z @ z^T (raw dots, fp32)
    gemm_nt<float, false><<<dim3(BATCH_N / 64, BATCH_N / 64), blk, 0, stream>>>(
        z, z, Sbuf, BATCH_N, BATCH_N, PROJ_D_, nullptr, nullptr);
    // simsq = mask(z @ queue^T) as fp16
    gemm_nt<__half, true><<<dim3(QUEUE_N / 64, BATCH_N / 64), blk, 0, stream>>>(
        z, queue, simsq, BATCH_N, QUEUE_N, PROJ_D_, labels, qlab);
    topk_lse<<<BATCH_N, 256, 0, stream>>>(simsq, lseq);
    batch_row_loss<<<BATCH_N, 256, 0, stream>>>(Sbuf, labels, lseq, accf, accc);
    finalize_loss<<<1, 64, 0, stream>>>(accf, accc, (float*)d_out);
}

// Round 2
// 422.186 us; speedup vs baseline: 1.4566x; 1.4566x over previous
//
#include <hip/hip_runtime.h>
#include <hip/hip_fp16.h>

#define BATCH_N   2048
#define EMB_D_    768
#define PROJ_D_   128
#define QUEUE_N   32768
#define HARD_K_   512
static constexpr float INV_T = 1.0f / 0.07f;

typedef __attribute__((ext_vector_type(8))) short short8;
typedef __attribute__((ext_vector_type(4))) short short4v;
typedef __attribute__((ext_vector_type(4))) float f32x4;

__device__ __forceinline__ unsigned short f2bf(float f) {
    unsigned u = __float_as_uint(f);
    unsigned r = u + 0x7fffu + ((u >> 16) & 1u);   // RNE
    return (unsigned short)(r >> 16);
}

// ---------------------------------------------------------------------------
// fp32 GEMM C = act(A @ B + bias): A (M x K) rm, B (K x N) rm. 64x64 tile.
// ---------------------------------------------------------------------------
template<bool RELU>
__global__ void __launch_bounds__(256) gemm_bias(const float* __restrict__ A,
                                                 const float* __restrict__ B,
                                                 const float* __restrict__ bias,
                                                 float* __restrict__ C,
                                                 int M, int N, int K) {
    __shared__ float As[16][68];
    __shared__ float Bs[16][68];
    const int t  = threadIdx.x;
    const int tx = t & 15, ty = t >> 4;
    const int m0 = blockIdx.y * 64, n0 = blockIdx.x * 64;
    const int arow = t >> 2, aks = (t & 3) * 4;
    const int bkk  = t >> 4, bns = (t & 15) * 4;
    float acc[4][4] = {};
    for (int k0 = 0; k0 < K; k0 += 16) {
        float4 av = *(const float4*)&A[(size_t)(m0 + arow) * K + k0 + aks];
        float4 bv = *(const float4*)&B[(size_t)(k0 + bkk) * N + n0 + bns];
        __syncthreads();
        As[aks + 0][arow] = av.x; As[aks + 1][arow] = av.y;
        As[aks + 2][arow] = av.z; As[aks + 3][arow] = av.w;
        *(float4*)&Bs[bkk][bns] = bv;
        __syncthreads();
        #pragma unroll
        for (int kk = 0; kk < 16; kk++) {
            float4 a4 = *(const float4*)&As[kk][ty * 4];
            float4 b4 = *(const float4*)&Bs[kk][tx * 4];
            float a[4] = {a4.x, a4.y, a4.z, a4.w};
            float b[4] = {b4.x, b4.y, b4.z, b4.w};
            #pragma unroll
            for (int i = 0; i < 4; i++)
                #pragma unroll
                for (int j = 0; j < 4; j++) acc[i][j] += a[i] * b[j];
        }
    }
    const int nbase = n0 + tx * 4;
    const float4 bb = *(const float4*)&bias[nbase];
    const float bs[4] = {bb.x, bb.y, bb.z, bb.w};
    #pragma unroll
    for (int i = 0; i < 4; i++) {
        int m = m0 + ty * 4 + i;
        float4 o;
        float v0 = acc[i][0] + bs[0], v1 = acc[i][1] + bs[1];
        float v2 = acc[i][2] + bs[2], v3 = acc[i][3] + bs[3];
        if (RELU) { v0 = fmaxf(v0, 0.f); v1 = fmaxf(v1, 0.f); v2 = fmaxf(v2, 0.f); v3 = fmaxf(v3, 0.f); }
        o.x = v0; o.y = v1; o.z = v2; o.w = v3;
        *(float4*)&C[(size_t)m * N + nbase] = o;
    }
}

// ---------------------------------------------------------------------------
// bf16 MFMA NT GEMM: C[m][n] = sum_k A[m][k]*B[n][k], K=128 (full depth in
// LDS, one barrier). A (M x 128) bf16 rm, B (N x 128) bf16 rm.
// 128x128 tile, 256 thr = 4 waves, each wave 64x64 via 4x4 tiles of 16x16x32.
// LDS chunk XOR-swizzle: elem block (row, chunk) at row*256B + (chunk^ (row&15))*16B
// -> global_load_lds stays lane-contiguous, ds_read_b128 frags 2-way (free).
// MASK: store fp16 with same/invalid-label -> -65504. else store fp32 raw.
// ---------------------------------------------------------------------------
template<typename OutT, bool MASK>
__global__ void __launch_bounds__(256) mfma_nt(const short* __restrict__ Ab,
                                               const short* __restrict__ Bb,
                                               OutT* __restrict__ C, int N,
                                               const int* __restrict__ labA,
                                               const int* __restrict__ labB) {
    __shared__ __align__(16) short As[128 * 128];
    __shared__ __align__(16) short Bs[128 * 128];
    const int t = threadIdx.x;
    const int lane = t & 63, wv = t >> 6;
    const int l16 = lane & 15, l4 = lane >> 4;
    const int m0 = blockIdx.y * 128, n0 = blockIdx.x * 128;

    // stage A tile (32 KB) + B tile (32 KB): 1 KB per wave-round
    #pragma unroll
    for (int it = 0; it < 8; ++it) {
        const int r   = it * 4 + wv;          // 0..31
        const int row = r * 4 + l4;
        const int cg  = l16 ^ (row & 15);
        __builtin_amdgcn_global_load_lds(
            (const __attribute__((address_space(1))) void*)(Ab + (size_t)(m0 + row) * 128 + cg * 8),
            (__attribute__((address_space(3))) void*)(As + r * 512), 16, 0, 0);
    }
    #pragma unroll
    for (int it = 0; it < 8; ++it) {
        const int r   = it * 4 + wv;
        const int row = r * 4 + l4;
        const int cg  = l16 ^ (row & 15);
        __builtin_amdgcn_global_load_lds(
            (const __attribute__((address_space(1))) void*)(Bb + (size_t)(n0 + row) * 128 + cg * 8),
            (__attribute__((address_space(3))) void*)(Bs + r * 512), 16, 0, 0);
    }
    __syncthreads();

    const int wm = (wv & 1) * 64, wn = (wv >> 1) * 64;
    f32x4 acc[4][4];
    #pragma unroll
    for (int i = 0; i < 4; ++i)
        #pragma unroll
        for (int j = 0; j < 4; ++j) acc[i][j] = f32x4{0.f, 0.f, 0.f, 0.f};

    #pragma unroll
    for (int ks = 0; ks < 4; ++ks) {
        short8 af[4], bfr[4];
        const int ch = (ks * 4 + l4) ^ l16;   // physical 16B-chunk index
        #pragma unroll
        for (int i = 0; i < 4; ++i) {
            const int rowA = wm + i * 16 + l16;
            af[i]  = *(const short8*)(As + rowA * 128 + ch * 8);
            const int rowB = wn + i * 16 + l16;
            bfr[i] = *(const short8*)(Bs + rowB * 128 + ch * 8);
        }
        #pragma unroll
        for (int i = 0; i < 4; ++i)
            #pragma unroll
            for (int j = 0; j < 4; ++j)
                acc[i][j] = __builtin_amdgcn_mfma_f32_16x16x32_bf16(af[i], bfr[j], acc[i][j], 0, 0, 0);
    }

    // epilogue: C/D layout col=lane&15, row=(lane>>4)*4+reg (m89/m91)
    int qn[4];
    if constexpr (MASK) {
        #pragma unroll
        for (int j = 0; j < 4; ++j) qn[j] = labB[n0 + wn + j * 16 + l16];
    }
    #pragma unroll
    for (int i = 0; i < 4; ++i) {
        #pragma unroll
        for (int r = 0; r < 4; ++r) {
            const int m = m0 + wm + i * 16 + l4 * 4 + r;
            if constexpr (MASK) {
                const int lm = labA[m];
                #pragma unroll
                for (int j = 0; j < 4; ++j) {
                    const int n = n0 + wn + j * 16 + l16;
                    const float v = (qn[j] != lm && qn[j] >= 0) ? acc[i][j][r] : -65504.0f;
                    ((__half*)C)[(size_t)m * N + n] = __float2half(v);
                }
            } else {
                #pragma unroll
                for (int j = 0; j < 4; ++j) {
                    const int n = n0 + wn + j * 16 + l16;
                    ((float*)C)[(size_t)m * N + n] = acc[i][j][r];
                }
            }
        }
    }
}

// ---------------------------------------------------------------------------
// Row L2-normalize z (2048 x 128) -> bf16 zb. One block (128 thr) per row.
// ---------------------------------------------------------------------------
__global__ void normalize_cast(const float* __restrict__ z, short* __restrict__ zb) {
    const int row = blockIdx.x, t = threadIdx.x;
    const float v = z[(size_t)row * PROJ_D_ + t];
    float ss = v * v;
    #pragma unroll
    for (int o = 32; o > 0; o >>= 1) ss += __shfl_down(ss, o);
    __shared__ float s2[2];
    if ((t & 63) == 0) s2[t >> 6] = ss;
    __syncthreads();
    const float tot = s2[0] + s2[1];
    zb[(size_t)row * PROJ_D_ + t] = (short)f2bf(v / sqrtf(tot));
}

// queue fp32 -> bf16, 4 elems/thread
__global__ void cast_bf16_vec(const float* __restrict__ src, short* __restrict__ dst, int n4) {
    const int i = blockIdx.x * blockDim.x + threadIdx.x;
    if (i < n4) {
        const float4 f = ((const float4*)src)[i];
        short4v o = {(short)f2bf(f.x), (short)f2bf(f.y), (short)f2bf(f.z), (short)f2bf(f.w)};
        ((short4v*)dst)[i] = o;
    }
}

// ---------------------------------------------------------------------------
// Histogram crossing search (unchanged, verified round 1)
// ---------------------------------------------------------------------------
__device__ __forceinline__ void find_crossing(int* hist, int* grp, int target,
                                              int* s_bin, int* s_chi) {
    const int t = threadIdx.x;
    const int b0 = hist[4*t], b1 = hist[4*t+1], b2 = hist[4*t+2], b3 = hist[4*t+3];
    grp[t] = b0 + b1 + b2 + b3;
    __syncthreads();
    for (int off = 1; off < 256; off <<= 1) {
        int add = (t + off < 256) ? grp[t + off] : 0;
        __syncthreads();
        grp[t] += add;
        __syncthreads();
    }
    int cab = (t < 255) ? grp[t + 1] : 0;
    const int hb[4] = {b0, b1, b2, b3};
    #pragma unroll
    for (int i = 3; i >= 0; i--) {
        const int h = hb[i];
        if (cab < target && cab + h >= target) { *s_bin = 4*t + i; *s_chi = cab; }
        cab += h;
    }
    __syncthreads();
}

// ---------------------------------------------------------------------------
// Per-row exact lse over top-512 of masked fp16 sims (unchanged, verified)
// ---------------------------------------------------------------------------
__global__ void __launch_bounds__(256) topk_lse(const __half* __restrict__ sims,
                                                float* __restrict__ lseq) {
    const int row = blockIdx.x, t = threadIdx.x;
    const uint4* rowp = (const uint4*)(sims + (size_t)row * QUEUE_N);
    __shared__ int hist[1024];
    __shared__ int grp[256];
    __shared__ int s_bin, s_chi, s_bin2, s_chi2;
    __shared__ float scf[4];
    __shared__ int sci[4];

    for (int k = t; k < 1024; k += 256) hist[k] = 0;
    __syncthreads();

    float mloc = -1e30f;
    for (int k = 0; k < 16; k++) {
        uint4 u = rowp[k * 256 + t];
        const __half2* hp = (const __half2*)&u;
        #pragma unroll
        for (int q = 0; q < 4; q++) {
            float2 f = __half22float2(hp[q]);
            #pragma unroll
            for (int e = 0; e < 2; e++) {
                const float v = e ? f.y : f.x;
                mloc = fmaxf(mloc, v);
                const float bf = fminf(fmaxf((v + 1.0f) * 512.0f, 0.0f), 1023.0f);
                atomicAdd(&hist[(int)bf], 1);
            }
        }
    }
    #pragma unroll
    for (int o = 32; o > 0; o >>= 1) mloc = fmaxf(mloc, __shfl_xor(mloc, o));
    if ((t & 63) == 0) scf[t >> 6] = mloc;
    __syncthreads();
    const float m = fmaxf(fmaxf(scf[0], scf[1]), fmaxf(scf[2], scf[3]));

    find_crossing(hist, grp, HARD_K_, &s_bin, &s_chi);
    const int   bin1 = s_bin;
    const int   chi1 = s_chi;
    const float lo   = -1.0f + bin1 * (1.0f / 512.0f);

    for (int k = t; k < 1024; k += 256) hist[k] = 0;
    __syncthreads();
    for (int k = 0; k < 16; k++) {
        uint4 u = rowp[k * 256 + t];
        const __half2* hp = (const __half2*)&u;
        #pragma unroll
        for (int q = 0; q < 4; q++) {
            float2 f = __half22float2(hp[q]);
            #pragma unroll
            for (int e = 0; e < 2; e++) {
                const float v = e ? f.y : f.x;
                const float bf = fminf(fmaxf((v + 1.0f) * 512.0f, 0.0f), 1023.0f);
                if ((int)bf == bin1) {
                    const float sf = fminf(fmaxf((v - lo) * 524288.0f, 0.0f), 1023.0f);
                    atomicAdd(&hist[(int)sf], 1);
                }
            }
        }
    }
    __syncthreads();
    find_crossing(hist, grp, HARD_K_ - chi1, &s_bin2, &s_chi2);
    const float thr = lo + s_bin2 * (1.0f / 524288.0f);

    float sl = 0.0f; int cg = 0;
    for (int k = 0; k < 16; k++) {
        uint4 u = rowp[k * 256 + t];
        const __half2* hp = (const __half2*)&u;
        #pragma unroll
        for (int q = 0; q < 4; q++) {
            float2 f = __half22float2(hp[q]);
            #pragma unroll
            for (int e = 0; e < 2; e++) {
                const float v = e ? f.y : f.x;
                if (v > thr) { cg++; sl += __expf((v - m) * INV_T); }
            }
        }
    }
    #pragma unroll
    for (int o = 32; o > 0; o >>= 1) { sl += __shfl_xor(sl, o); cg += __shfl_xor(cg, o); }
    if ((t & 63) == 0) { scf[t >> 6] = sl; sci[t >> 6] = cg; }
    __syncthreads();
    if (t == 0) {
        const float slt = scf[0] + scf[1] + scf[2] + scf[3];
        const int   cgt = sci[0] + sci[1] + sci[2] + sci[3];
        const float sadj = slt + ((float)HARD_K_ - (float)cgt) * __expf((thr - m) * INV_T);
        lseq[row] = m * INV_T + __logf(sadj);
    }
}

// ---------------------------------------------------------------------------
// Per-row batch lse + positive-pair loss (unchanged, verified)
// ---------------------------------------------------------------------------
__global__ void __launch_bounds__(256) batch_row_loss(const float* __restrict__ S,
                                                      const int* __restrict__ labels,
                                                      const float* __restrict__ lse_queue,
                                                      float* __restrict__ loss_sum,
                                                      unsigned int* __restrict__ pair_count) {
    const int row = blockIdx.x, t = threadIdx.x;
    __shared__ int lab[BATCH_N];
    __shared__ float wm[4], wsum[4], Lsh;
    __shared__ float rp[4]; __shared__ int rc[4];
    for (int k = t; k < BATCH_N; k += 256) lab[k] = labels[k];
    __syncthreads();
    const int myLab = lab[row];
    const float* rowp = S + (size_t)row * BATCH_N;

    float v[8];
    float mm = -1e30f, ss = 0.0f;
    #pragma unroll
    for (int k = 0; k < 8; k++) {
        const int j = t + 256 * k;
        v[k] = rowp[j] * INV_T;
        if (lab[j] != myLab) {
            const float sv = v[k];
            if (sv > mm) { ss = ss * __expf(mm - sv) + 1.0f; mm = sv; }
            else         { ss += __expf(sv - mm); }
        }
    }
    #pragma unroll
    for (int o = 32; o > 0; o >>= 1) {
        const float om = __shfl_xor(mm, o), os = __shfl_xor(ss, o);
        const float nm = fmaxf(mm, om);
        ss = ss * __expf(mm - nm) + os * __expf(om - nm);
        mm = nm;
    }
    if ((t & 63) == 0) { wm[t >> 6] = mm; wsum[t >> 6] = ss; }
    __syncthreads();
    if (t == 0) {
        float M = -1e30f, Sx = 0.0f;
        for (int w = 0; w < 4; w++) {
            const float nm = fmaxf(M, wm[w]);
            Sx = Sx * __expf(M - nm) + wsum[w] * __expf(wm[w] - nm);
            M = nm;
        }
        const float lseb = (Sx > 0.0f) ? M + __logf(Sx) : -1e30f;
        const float Lq = lse_queue[row];
        const float mx = fmaxf(lseb, Lq), mn = fminf(lseb, Lq);
        Lsh = mx + log1pf(__expf(mn - mx));
    }
    __syncthreads();
    const float L = Lsh;

    float part = 0.0f; int cnt = 0;
    #pragma unroll
    for (int k = 0; k < 8; k++) {
        const int j = t + 256 * k;
        if (lab[j] == myLab && j != row) {
            const float sv = v[k];
            const float mx = fmaxf(sv, L), mn = fminf(sv, L);
            part += (mx + log1pf(__expf(mn - mx))) - sv;
            cnt++;
        }
    }
    #pragma unroll
    for (int o = 32; o > 0; o >>= 1) { part += __shfl_xor(part, o); cnt += __shfl_xor(cnt, o); }
    if ((t & 63) == 0) { rp[t >> 6] = part; rc[t >> 6] = cnt; }
    __syncthreads();
    if (t == 0) {
        atomicAdd(loss_sum, rp[0] + rp[1] + rp[2] + rp[3]);
        atomicAdd(pair_count, (unsigned int)(rc[0] + rc[1] + rc[2] + rc[3]));
    }
}

__global__ void finalize_loss(const float* __restrict__ loss_sum,
                              const unsigned int* __restrict__ cnt,
                              float* __restrict__ out) {
    if (blockIdx.x == 0 && threadIdx.x == 0) {
        const unsigned int c = *cnt;
        out[0] = (c > 0) ? (*loss_sum / (float)c) : 0.0f;
    }
}

// ---------------------------------------------------------------------------
extern "C" void kernel_launch(void* const* d_in, const int* in_sizes, int n_in,
                              void* d_out, int out_size, void* d_ws, size_t ws_size,
                              hipStream_t stream) {
    const float* emb    = (const float*)d_in[0];
    const int*   labels = (const int*)  d_in[1];
    const float* W1     = (const float*)d_in[2];
    const float* b1     = (const float*)d_in[3];
    const float* W2     = (const float*)d_in[4];
    const float* b2     = (const float*)d_in[5];
    const float* queue  = (const float*)d_in[6];
    const int*   qlab   = (const int*)  d_in[7];

    char* ws = (char*)d_ws;
    // layout (bytes) — Sbuf overlays simsq (computed after topk consumes it)
    __half* simsq = (__half*)(ws);                       // [0, 134217728)
    float*  Sbuf  = (float*) (ws);                       // [0, 16777216)  (after topk)
    float*  h     = (float*) (ws + 134217728);           // 6291456
    float*  z     = (float*) (ws + 140509184);           // 1048576
    short*  zb    = (short*) (ws + 141557760);           // 524288
    short*  qb    = (short*) (ws + 142082048);           // 8388608
    float*  lseq  = (float*) (ws + 150470656);           // 8192
    float*         accf = (float*)       (ws + 150478848);
    unsigned int*  accc = (unsigned int*)(ws + 150478852);

    hipMemsetAsync(ws + 150478848, 0, 8, stream);

    dim3 blk(256);
    gemm_bias<true ><<<dim3(EMB_D_ / 64, BATCH_N / 64), blk, 0, stream>>>(emb, W1, b1, h, BATCH_N, EMB_D_, EMB_D_);
    gemm_bias<false><<<dim3(PROJ_D_ / 64, BATCH_N / 64), blk, 0, stream>>>(h, W2, b2, z, BATCH_N, PROJ_D_, EMB_D_);
    normalize_cast<<<BATCH_N, PROJ_D_, 0, stream>>>(z, zb);
    cast_bf16_vec<<<dim3(QUEUE_N * PROJ_D_ / 4 / 256), blk, 0, stream>>>(queue, qb, QUEUE_N * PROJ_D_ / 4);
    // simsq = mask(z @ queue^T) fp16 via bf16 MFMA
    mfma_nt<__half, true><<<dim3(QUEUE_N / 128, BATCH_N / 128), blk, 0, stream>>>(
        zb, qb, simsq, QUEUE_N, labels, qlab);
    topk_lse<<<BATCH_N, 256, 0, stream>>>(simsq, lseq);
    // S = z @ z^T fp32 via bf16 MFMA (overlays simsq region)
    mfma_nt<float, false><<<dim3(BATCH_N / 128, BATCH_N / 128), blk, 0, stream>>>(
        zb, zb, Sbuf, BATCH_N, nullptr, nullptr);
    batch_row_loss<<<BATCH_N, 256, 0, stream>>>(Sbuf, labels, lseq, accf, accc);
    finalize_loss<<<1, 64, 0, stream>>>(accf, accc, (float*)d_out);
}

// Round 3
// 395.733 us; speedup vs baseline: 1.5540x; 1.0668x over previous
//
#include <hip/hip_runtime.h>
#include <hip/hip_fp16.h>

#define BATCH_N   2048
#define EMB_D_    768
#define PROJ_D_   128
#define QUEUE_N   32768
#define HARD_K_   512
static constexpr float INV_T = 1.0f / 0.07f;

typedef __attribute__((ext_vector_type(8))) short short8;
typedef __attribute__((ext_vector_type(4))) short short4v;
typedef __attribute__((ext_vector_type(4))) float f32x4;

__device__ __forceinline__ unsigned short f2bf(float f) {
    unsigned u = __float_as_uint(f);
    unsigned r = u + 0x7fffu + ((u >> 16) & 1u);   // RNE
    return (unsigned short)(r >> 16);
}

// ---------------------------------------------------------------------------
// bf16 MFMA NT GEMM, K=128 fully in LDS (verified r2). 128x128 tile, 4 waves.
// XOR chunk swizzle. MASK: fp16 store, same/invalid label -> -65504.
// ---------------------------------------------------------------------------
template<typename OutT, bool MASK>
__global__ void __launch_bounds__(256) mfma_nt(const short* __restrict__ Ab,
                                               const short* __restrict__ Bb,
                                               OutT* __restrict__ C, int N,
                                               const int* __restrict__ labA,
                                               const int* __restrict__ labB) {
    __shared__ __align__(16) short As[128 * 128];
    __shared__ __align__(16) short Bs[128 * 128];
    const int t = threadIdx.x;
    const int lane = t & 63, wv = t >> 6;
    const int l16 = lane & 15, l4 = lane >> 4;
    const int m0 = blockIdx.y * 128, n0 = blockIdx.x * 128;

    #pragma unroll
    for (int it = 0; it < 8; ++it) {
        const int r   = it * 4 + wv;
        const int row = r * 4 + l4;
        const int cg  = l16 ^ (row & 15);
        __builtin_amdgcn_global_load_lds(
            (const __attribute__((address_space(1))) void*)(Ab + (size_t)(m0 + row) * 128 + cg * 8),
            (__attribute__((address_space(3))) void*)(As + r * 512), 16, 0, 0);
    }
    #pragma unroll
    for (int it = 0; it < 8; ++it) {
        const int r   = it * 4 + wv;
        const int row = r * 4 + l4;
        const int cg  = l16 ^ (row & 15);
        __builtin_amdgcn_global_load_lds(
            (const __attribute__((address_space(1))) void*)(Bb + (size_t)(n0 + row) * 128 + cg * 8),
            (__attribute__((address_space(3))) void*)(Bs + r * 512), 16, 0, 0);
    }
    __syncthreads();

    const int wm = (wv & 1) * 64, wn = (wv >> 1) * 64;
    f32x4 acc[4][4];
    #pragma unroll
    for (int i = 0; i < 4; ++i)
        #pragma unroll
        for (int j = 0; j < 4; ++j) acc[i][j] = f32x4{0.f, 0.f, 0.f, 0.f};

    #pragma unroll
    for (int ks = 0; ks < 4; ++ks) {
        short8 af[4], bfr[4];
        const int ch = (ks * 4 + l4) ^ l16;
        #pragma unroll
        for (int i = 0; i < 4; ++i) {
            af[i]  = *(const short8*)(As + (wm + i * 16 + l16) * 128 + ch * 8);
            bfr[i] = *(const short8*)(Bs + (wn + i * 16 + l16) * 128 + ch * 8);
        }
        #pragma unroll
        for (int i = 0; i < 4; ++i)
            #pragma unroll
            for (int j = 0; j < 4; ++j)
                acc[i][j] = __builtin_amdgcn_mfma_f32_16x16x32_bf16(af[i], bfr[j], acc[i][j], 0, 0, 0);
    }

    int qn[4];
    if constexpr (MASK) {
        #pragma unroll
        for (int j = 0; j < 4; ++j) qn[j] = labB[n0 + wn + j * 16 + l16];
    }
    #pragma unroll
    for (int i = 0; i < 4; ++i) {
        #pragma unroll
        for (int r = 0; r < 4; ++r) {
            const int m = m0 + wm + i * 16 + l4 * 4 + r;
            if constexpr (MASK) {
                const int lm = labA[m];
                #pragma unroll
                for (int j = 0; j < 4; ++j) {
                    const int n = n0 + wn + j * 16 + l16;
                    const float v = (qn[j] != lm && qn[j] >= 0) ? acc[i][j][r] : -65504.0f;
                    ((__half*)C)[(size_t)m * N + n] = __float2half(v);
                }
            } else {
                #pragma unroll
                for (int j = 0; j < 4; ++j) {
                    const int n = n0 + wn + j * 16 + l16;
                    ((float*)C)[(size_t)m * N + n] = acc[i][j][r];
                }
            }
        }
    }
}

// ---------------------------------------------------------------------------
// bf16 MFMA NT GEMM with K-loop (BK=128), fused bias (+optional ReLU).
// A (M x K) bf16 rm, B (N x K) bf16 rm (pre-transposed weights), bias fp32.
// OutT: short (bf16) or float.
// ---------------------------------------------------------------------------
template<typename OutT, bool RELU>
__global__ void __launch_bounds__(256) mfma_nt_k(const short* __restrict__ Ab,
                                                 const short* __restrict__ Bb,
                                                 const float* __restrict__ bias,
                                                 OutT* __restrict__ C,
                                                 int N, int K) {
    __shared__ __align__(16) short As[128 * 128];
    __shared__ __align__(16) short Bs[128 * 128];
    const int t = threadIdx.x;
    const int lane = t & 63, wv = t >> 6;
    const int l16 = lane & 15, l4 = lane >> 4;
    const int m0 = blockIdx.y * 128, n0 = blockIdx.x * 128;
    const int wm = (wv & 1) * 64, wn = (wv >> 1) * 64;

    f32x4 acc[4][4];
    #pragma unroll
    for (int i = 0; i < 4; ++i)
        #pragma unroll
        for (int j = 0; j < 4; ++j) acc[i][j] = f32x4{0.f, 0.f, 0.f, 0.f};

    for (int kb = 0; kb < K; kb += 128) {
        __syncthreads();
        #pragma unroll
        for (int it = 0; it < 8; ++it) {
            const int r   = it * 4 + wv;
            const int row = r * 4 + l4;
            const int cg  = l16 ^ (row & 15);
            __builtin_amdgcn_global_load_lds(
                (const __attribute__((address_space(1))) void*)(Ab + (size_t)(m0 + row) * K + kb + cg * 8),
                (__attribute__((address_space(3))) void*)(As + r * 512), 16, 0, 0);
        }
        #pragma unroll
        for (int it = 0; it < 8; ++it) {
            const int r   = it * 4 + wv;
            const int row = r * 4 + l4;
            const int cg  = l16 ^ (row & 15);
            __builtin_amdgcn_global_load_lds(
                (const __attribute__((address_space(1))) void*)(Bb + (size_t)(n0 + row) * K + kb + cg * 8),
                (__attribute__((address_space(3))) void*)(Bs + r * 512), 16, 0, 0);
        }
        __syncthreads();
        #pragma unroll
        for (int ks = 0; ks < 4; ++ks) {
            short8 af[4], bfr[4];
            const int ch = (ks * 4 + l4) ^ l16;
            #pragma unroll
            for (int i = 0; i < 4; ++i) {
                af[i]  = *(const short8*)(As + (wm + i * 16 + l16) * 128 + ch * 8);
                bfr[i] = *(const short8*)(Bs + (wn + i * 16 + l16) * 128 + ch * 8);
            }
            #pragma unroll
            for (int i = 0; i < 4; ++i)
                #pragma unroll
                for (int j = 0; j < 4; ++j)
                    acc[i][j] = __builtin_amdgcn_mfma_f32_16x16x32_bf16(af[i], bfr[j], acc[i][j], 0, 0, 0);
        }
    }

    float bsv[4];
    #pragma unroll
    for (int j = 0; j < 4; ++j) bsv[j] = bias[n0 + wn + j * 16 + l16];
    #pragma unroll
    for (int i = 0; i < 4; ++i) {
        #pragma unroll
        for (int r = 0; r < 4; ++r) {
            const int m = m0 + wm + i * 16 + l4 * 4 + r;
            #pragma unroll
            for (int j = 0; j < 4; ++j) {
                const int n = n0 + wn + j * 16 + l16;
                float v = acc[i][j][r] + bsv[j];
                if (RELU) v = fmaxf(v, 0.0f);
                if constexpr (sizeof(OutT) == 2) ((short*)C)[(size_t)m * N + n] = (short)f2bf(v);
                else                             ((float*)C)[(size_t)m * N + n] = v;
            }
        }
    }
}

// ---------------------------------------------------------------------------
// Transpose + cast: A (R x C) fp32 -> At (C x R) bf16. 64x64 tiles, 256 thr.
// ---------------------------------------------------------------------------
__global__ void __launch_bounds__(256) transpose_cast(const float* __restrict__ A,
                                                      short* __restrict__ At,
                                                      int R, int C) {
    __shared__ float tile[64][65];
    const int bx = blockIdx.x * 64;   // col base
    const int by = blockIdx.y * 64;   // row base
    const int t = threadIdx.x, tc = t & 63, tg = t >> 6;
    #pragma unroll
    for (int i = 0; i < 16; i++) {
        const int r = tg * 16 + i;
        tile[r][tc] = A[(size_t)(by + r) * C + bx + tc];
    }
    __syncthreads();
    #pragma unroll
    for (int i = 0; i < 16; i++) {
        const int r = tg * 16 + i;
        At[(size_t)(bx + r) * R + by + tc] = (short)f2bf(tile[tc][r]);
    }
}

// ---------------------------------------------------------------------------
// Row L2-normalize z (2048 x 128) -> bf16 zb.
// ---------------------------------------------------------------------------
__global__ void normalize_cast(const float* __restrict__ z, short* __restrict__ zb) {
    const int row = blockIdx.x, t = threadIdx.x;
    const float v = z[(size_t)row * PROJ_D_ + t];
    float ss = v * v;
    #pragma unroll
    for (int o = 32; o > 0; o >>= 1) ss += __shfl_down(ss, o);
    __shared__ float s2[2];
    if ((t & 63) == 0) s2[t >> 6] = ss;
    __syncthreads();
    const float tot = s2[0] + s2[1];
    zb[(size_t)row * PROJ_D_ + t] = (short)f2bf(v / sqrtf(tot));
}

__global__ void cast_bf16_vec(const float* __restrict__ src, short* __restrict__ dst, int n4) {
    const int i = blockIdx.x * blockDim.x + threadIdx.x;
    if (i < n4) {
        const float4 f = ((const float4*)src)[i];
        short4v o = {(short)f2bf(f.x), (short)f2bf(f.y), (short)f2bf(f.z), (short)f2bf(f.w)};
        ((short4v*)dst)[i] = o;
    }
}

// ---------------------------------------------------------------------------
// Histogram crossing search (verified r1/r2)
// ---------------------------------------------------------------------------
__device__ __forceinline__ void find_crossing(int* hist, int* grp, int target,
                                              int* s_bin, int* s_chi) {
    const int t = threadIdx.x;
    const int b0 = hist[4*t], b1 = hist[4*t+1], b2 = hist[4*t+2], b3 = hist[4*t+3];
    grp[t] = b0 + b1 + b2 + b3;
    __syncthreads();
    for (int off = 1; off < 256; off <<= 1) {
        int add = (t + off < 256) ? grp[t + off] : 0;
        __syncthreads();
        grp[t] += add;
        __syncthreads();
    }
    int cab = (t < 255) ? grp[t + 1] : 0;
    const int hb[4] = {b0, b1, b2, b3};
    #pragma unroll
    for (int i = 3; i >= 0; i--) {
        const int h = hb[i];
        if (cab < target && cab + h >= target) { *s_bin = 4*t + i; *s_chi = cab; }
        cab += h;
    }
    __syncthreads();
}

// iterate all 128 row values held in regs: dv[64] packed half2
#define FOR_ALL_VALS(BODY)                                                   \
    _Pragma("unroll")                                                        \
    for (int _k = 0; _k < 64; _k++) {                                        \
        const float2 _f = __half22float2(*(const __half2*)&dv[_k]);          \
        { const float v = _f.x; BODY }                                       \
        { const float v = _f.y; BODY }                                       \
    }

// ---------------------------------------------------------------------------
// Register-resident top-512 lse. One block (256 thr) per row; 128 fp16/thread.
// Adaptive histogram window [m-R, m] so only tail elements touch LDS atomics.
// ---------------------------------------------------------------------------
__global__ void __launch_bounds__(256) topk_lse(const __half* __restrict__ sims,
                                                float* __restrict__ lseq) {
    const int row = blockIdx.x, t = threadIdx.x;
    const uint4* rowp = (const uint4*)(sims + (size_t)row * QUEUE_N);
    __shared__ int hist[1024];
    __shared__ int grp[256];
    __shared__ int s_bin, s_chi, s_bin2, s_chi2;
    __shared__ float scf[4];
    __shared__ int sci[4][3];

    unsigned dv[64];
    #pragma unroll
    for (int k = 0; k < 16; k++) {
        const uint4 u = rowp[k * 256 + t];
        dv[4*k] = u.x; dv[4*k+1] = u.y; dv[4*k+2] = u.z; dv[4*k+3] = u.w;
    }

    // row max
    float mloc = -1e30f;
    FOR_ALL_VALS( mloc = fmaxf(mloc, v); )
    #pragma unroll
    for (int o = 32; o > 0; o >>= 1) mloc = fmaxf(mloc, __shfl_xor(mloc, o));
    if ((t & 63) == 0) scf[t >> 6] = mloc;
    __syncthreads();
    const float m = fmaxf(fmaxf(scf[0], scf[1]), fmaxf(scf[2], scf[3]));

    // window-selection counts
    int c1 = 0, c2 = 0, c3 = 0;
    const float w1 = m - 0.25f, w2 = m - 1.0f;
    FOR_ALL_VALS( c1 += (v >= w1); c2 += (v >= w2); c3 += (v >= -1.01f); )
    #pragma unroll
    for (int o = 32; o > 0; o >>= 1) { c1 += __shfl_xor(c1, o); c2 += __shfl_xor(c2, o); c3 += __shfl_xor(c3, o); }
    if ((t & 63) == 0) { sci[t >> 6][0] = c1; sci[t >> 6][1] = c2; sci[t >> 6][2] = c3; }
    __syncthreads();
    const int C1 = sci[0][0] + sci[1][0] + sci[2][0] + sci[3][0];
    const int C2 = sci[0][1] + sci[1][1] + sci[2][1] + sci[3][1];
    const int C3 = sci[0][2] + sci[1][2] + sci[2][2] + sci[3][2];

    float thr;
    if (C3 >= HARD_K_) {               // block-uniform branch
        float lo;
        if      (C1 >= HARD_K_) lo = w1;
        else if (C2 >= HARD_K_) lo = w2;
        else                    lo = -1.01f;
        const float range = m - lo;
        const float scale = 1024.0f / range;

        for (int k = t; k < 1024; k += 256) hist[k] = 0;
        __syncthreads();
        FOR_ALL_VALS(
            if (v >= lo) {
                const float bf = fminf((v - lo) * scale, 1023.0f);
                atomicAdd(&hist[(int)bf], 1);
            } )
        __syncthreads();
        find_crossing(hist, grp, HARD_K_, &s_bin, &s_chi);
        const int   bin1 = s_bin;
        const int   chi1 = s_chi;
        const float binw = range * (1.0f / 1024.0f);
        const float lo1  = lo + bin1 * binw;
        const float sscale = 1024.0f / binw;

        for (int k = t; k < 1024; k += 256) hist[k] = 0;
        __syncthreads();
        FOR_ALL_VALS(
            if (v >= lo) {
                const float bf = fminf((v - lo) * scale, 1023.0f);
                if ((int)bf == bin1) {
                    const float sf = fminf(fmaxf((v - lo1) * sscale, 0.0f), 1023.0f);
                    atomicAdd(&hist[(int)sf], 1);
                }
            } )
        __syncthreads();
        find_crossing(hist, grp, HARD_K_ - chi1, &s_bin2, &s_chi2);
        thr = lo1 + s_bin2 * (binw * (1.0f / 1024.0f));
    } else {
        thr = -2.0f;                    // <512 valid: the rest contribute ~exp(-2/T)=0
    }

    // exp-sum over v > thr, compensate boundary count to exactly 512
    float sl = 0.0f; int cg = 0;
    FOR_ALL_VALS( if (v > thr) { cg++; sl += __expf((v - m) * INV_T); } )
    #pragma unroll
    for (int o = 32; o > 0; o >>= 1) { sl += __shfl_xor(sl, o); cg += __shfl_xor(cg, o); }
    if ((t & 63) == 0) { scf[t >> 6] = sl; sci[t >> 6][0] = cg; }
    __syncthreads();
    if (t == 0) {
        const float slt = scf[0] + scf[1] + scf[2] + scf[3];
        const int   cgt = sci[0][0] + sci[1][0] + sci[2][0] + sci[3][0];
        const float sadj = slt + ((float)HARD_K_ - (float)cgt) * __expf((thr - m) * INV_T);
        lseq[row] = m * INV_T + __logf(sadj);
    }
}

// ---------------------------------------------------------------------------
// Per-row batch lse + positive-pair loss (verified r1/r2)
// ---------------------------------------------------------------------------
__global__ void __launch_bounds__(256) batch_row_loss(const float* __restrict__ S,
                                                      const int* __restrict__ labels,
                                                      const float* __restrict__ lse_queue,
                                                      float* __restrict__ loss_sum,
                                                      unsigned int* __restrict__ pair_count) {
    const int row = blockIdx.x, t = threadIdx.x;
    __shared__ int lab[BATCH_N];
    __shared__ float wm[4], wsum[4], Lsh;
    __shared__ float rp[4]; __shared__ int rc[4];
    for (int k = t; k < BATCH_N; k += 256) lab[k] = labels[k];
    __syncthreads();
    const int myLab = lab[row];
    const float* rowp = S + (size_t)row * BATCH_N;

    float v[8];
    float mm = -1e30f, ss = 0.0f;
    #pragma unroll
    for (int k = 0; k < 8; k++) {
        const int j = t + 256 * k;
        v[k] = rowp[j] * INV_T;
        if (lab[j] != myLab) {
            const float sv = v[k];
            if (sv > mm) { ss = ss * __expf(mm - sv) + 1.0f; mm = sv; }
            else         { ss += __expf(sv - mm); }
        }
    }
    #pragma unroll
    for (int o = 32; o > 0; o >>= 1) {
        const float om = __shfl_xor(mm, o), os = __shfl_xor(ss, o);
        const float nm = fmaxf(mm, om);
        ss = ss * __expf(mm - nm) + os * __expf(om - nm);
        mm = nm;
    }
    if ((t & 63) == 0) { wm[t >> 6] = mm; wsum[t >> 6] = ss; }
    __syncthreads();
    if (t == 0) {
        float M = -1e30f, Sx = 0.0f;
        for (int w = 0; w < 4; w++) {
            const float nm = fmaxf(M, wm[w]);
            Sx = Sx * __expf(M - nm) + wsum[w] * __expf(wm[w] - nm);
            M = nm;
        }
        const float lseb = (Sx > 0.0f) ? M + __logf(Sx) : -1e30f;
        const float Lq = lse_queue[row];
        const float mx = fmaxf(lseb, Lq), mn = fminf(lseb, Lq);
        Lsh = mx + log1pf(__expf(mn - mx));
    }
    __syncthreads();
    const float L = Lsh;

    float part = 0.0f; int cnt = 0;
    #pragma unroll
    for (int k = 0; k < 8; k++) {
        const int j = t + 256 * k;
        if (lab[j] == myLab && j != row) {
            const float sv = v[k];
            const float mx = fmaxf(sv, L), mn = fminf(sv, L);
            part += (mx + log1pf(__expf(mn - mx))) - sv;
            cnt++;
        }
    }
    #pragma unroll
    for (int o = 32; o > 0; o >>= 1) { part += __shfl_xor(part, o); cnt += __shfl_xor(cnt, o); }
    if ((t & 63) == 0) { rp[t >> 6] = part; rc[t >> 6] = cnt; }
    __syncthreads();
    if (t == 0) {
        atomicAdd(loss_sum, rp[0] + rp[1] + rp[2] + rp[3]);
        atomicAdd(pair_count, (unsigned int)(rc[0] + rc[1] + rc[2] + rc[3]));
    }
}

__global__ void finalize_loss(const float* __restrict__ loss_sum,
                              const unsigned int* __restrict__ cnt,
                              float* __restrict__ out) {
    if (blockIdx.x == 0 && threadIdx.x == 0) {
        const unsigned int c = *cnt;
        out[0] = (c > 0) ? (*loss_sum / (float)c) : 0.0f;
    }
}

// ---------------------------------------------------------------------------
extern "C" void kernel_launch(void* const* d_in, const int* in_sizes, int n_in,
                              void* d_out, int out_size, void* d_ws, size_t ws_size,
                              hipStream_t stream) {
    const float* emb    = (const float*)d_in[0];
    const int*   labels = (const int*)  d_in[1];
    const float* W1     = (const float*)d_in[2];
    const float* b1     = (const float*)d_in[3];
    const float* W2     = (const float*)d_in[4];
    const float* b2     = (const float*)d_in[5];
    const float* queue  = (const float*)d_in[6];
    const int*   qlab   = (const int*)  d_in[7];

    char* ws = (char*)d_ws;
    __half* simsq = (__half*)(ws);                       // [0, 134217728)
    float*  Sbuf  = (float*) (ws);                       // overlays simsq post-topk
    short*  embb  = (short*) (ws + 134217728);           // 3145728
    short*  hbf   = (short*) (ws + 137363456);           // 3145728
    float*  z     = (float*) (ws + 140509184);           // 1048576
    short*  zb    = (short*) (ws + 141557760);           // 524288
    short*  qb    = (short*) (ws + 142082048);           // 8388608
    short*  w1t   = (short*) (ws + 150470656);           // 1179648
    short*  w2t   = (short*) (ws + 151650304);           // 196608
    float*  lseq  = (float*) (ws + 151846912);           // 8192
    float*         accf = (float*)       (ws + 151855104);
    unsigned int*  accc = (unsigned int*)(ws + 151855108);

    hipMemsetAsync(ws + 151855104, 0, 8, stream);

    dim3 blk(256);
    // casts / transposes
    cast_bf16_vec<<<dim3(BATCH_N * EMB_D_ / 4 / 256), blk, 0, stream>>>(emb, embb, BATCH_N * EMB_D_ / 4);
    cast_bf16_vec<<<dim3(QUEUE_N * PROJ_D_ / 4 / 256), blk, 0, stream>>>(queue, qb, QUEUE_N * PROJ_D_ / 4);
    transpose_cast<<<dim3(EMB_D_ / 64, EMB_D_ / 64), blk, 0, stream>>>(W1, w1t, EMB_D_, EMB_D_);
    transpose_cast<<<dim3(PROJ_D_ / 64, EMB_D_ / 64), blk, 0, stream>>>(W2, w2t, EMB_D_, PROJ_D_);
    // MLP on MFMA
    mfma_nt_k<short, true ><<<dim3(EMB_D_ / 128, BATCH_N / 128), blk, 0, stream>>>(embb, w1t, b1, hbf, EMB_D_, EMB_D_);
    mfma_nt_k<float, false><<<dim3(PROJ_D_ / 128, BATCH_N / 128), blk, 0, stream>>>(hbf, w2t, b2, z, PROJ_D_, EMB_D_);
    normalize_cast<<<BATCH_N, PROJ_D_, 0, stream>>>(z, zb);
    // simsq = mask(z @ queue^T) fp16
    mfma_nt<__half, true><<<dim3(QUEUE_N / 128, BATCH_N / 128), blk, 0, stream>>>(
        zb, qb, simsq, QUEUE_N, labels, qlab);
    topk_lse<<<BATCH_N, 256, 0, stream>>>(simsq, lseq);
    // S = z @ z^T fp32 (overlays simsq)
    mfma_nt<float, false><<<dim3(BATCH_N / 128, BATCH_N / 128), blk, 0, stream>>>(
        zb, zb, Sbuf, BATCH_N, nullptr, nullptr);
    batch_row_loss<<<BATCH_N, 256, 0, stream>>>(Sbuf, labels, lseq, accf, accc);
    finalize_loss<<<1, 64, 0, stream>>>(accf, accc, (float*)d_out);
}